// Round 1
// baseline (489.161 us; speedup 1.0000x reference)
//
#include <hip/hip_runtime.h>

#define NL 8
#define BPL 524288
#define NB (NL * BPL)            // 4194304 buckets
#define NS 8
#define GRAV 9.8f

// ---------------------------------------------------------------------------
// Kernel 1: one thread per spigot (NB*NS = 33.5M threads).
// Fully coalesced: theta dword, S float2, s_q dword store. H broadcast per
// 8-lane group. Per-bucket outflow via 3-step shfl_xor reduction; stored to
// workspace (if available).
// 0.5*(tanh(h)+1) == 1/(1+exp(-2h)) -> v_exp + v_rcp instead of tanh.
// ---------------------------------------------------------------------------
__global__ __launch_bounds__(256) void spigot_kernel(
    const float* __restrict__ H,
    const float* __restrict__ S,
    const float* __restrict__ theta,
    float* __restrict__ s_q,
    float* __restrict__ outflows)   // may be nullptr (fallback path)
{
    const int tid    = blockIdx.x * 256 + threadIdx.x;  // spigot index
    const int bucket = tid >> 3;

    const float  th = theta[tid];
    const float2 sv = reinterpret_cast<const float2*>(S)[tid];  // (height, area)
    const float  Hb = H[bucket];

    const float h   = fmaxf(0.0f, Hb - sv.x);
    const float e   = __expf(-2.0f * h);
    const float mod = __builtin_amdgcn_rcpf(1.0f + e);          // sigmoid(2h)
    const float v   = th * __builtin_amdgcn_sqrtf(2.0f * GRAV * h) * mod;
    const float q   = v * sv.y;

    s_q[tid] = q;

    if (outflows != nullptr) {
        // reduce the 8 spigots of this bucket (8 consecutive lanes)
        float sum = q;
        sum += __shfl_xor(sum, 1);
        sum += __shfl_xor(sum, 2);
        sum += __shfl_xor(sum, 4);
        if ((threadIdx.x & 7) == 0) outflows[bucket] = sum;
    }
}

// ---------------------------------------------------------------------------
// Kernel 2 (primary): H_new[i] = H[i] + inflow[i] - outflow[i],
// inflow[i] = (i==0) ? precip : outflows[i-1]. float4 over buckets
// (1024 buckets/block). Also accumulates network_outflow = sum of outflows
// over the last layer: wave reduce -> LDS -> 1 atomic per block (512 blocks).
// ---------------------------------------------------------------------------
__global__ __launch_bounds__(256) void head_kernel(
    const float* __restrict__ H,
    const float* __restrict__ outflows,
    const float* __restrict__ precip,
    float* __restrict__ H_new,
    float* __restrict__ net_out)
{
    const int t = blockIdx.x * 256 + threadIdx.x;  // float4 index
    const int i = t << 2;                          // bucket base

    const float4 o  = reinterpret_cast<const float4*>(outflows)[t];
    const float4 Hv = reinterpret_cast<const float4*>(H)[t];
    const float om1 = (i == 0) ? precip[0] : outflows[i - 1];

    float4 hn;
    hn.x = Hv.x + om1 - o.x;
    hn.y = Hv.y + o.x - o.y;
    hn.z = Hv.z + o.y - o.z;
    hn.w = Hv.w + o.z - o.w;
    reinterpret_cast<float4*>(H_new)[t] = hn;

    // ---- network_outflow partial (blocks >= 3584 cover the last layer) ----
    float part = (o.x + o.y) + (o.z + o.w);
    part += __shfl_xor(part, 1);
    part += __shfl_xor(part, 2);
    part += __shfl_xor(part, 4);
    part += __shfl_xor(part, 8);
    part += __shfl_xor(part, 16);
    part += __shfl_xor(part, 32);

    __shared__ float smem[4];
    const int lane = threadIdx.x & 63;
    const int w    = threadIdx.x >> 6;
    if (lane == 0) smem[w] = part;
    __syncthreads();
    if (threadIdx.x == 0 && blockIdx.x >= ((NB - BPL) >> 10)) {
        atomicAdd(net_out, (smem[0] + smem[1]) + (smem[2] + smem[3]));
    }
}

// ---------------------------------------------------------------------------
// Kernel 2 (fallback, no workspace): recompute bucket sums from s_q.
// One thread per bucket; reads own + previous bucket's 8 spigots (L2 absorbs
// the 2x overlap).
// ---------------------------------------------------------------------------
__global__ __launch_bounds__(256) void head_kernel_nows(
    const float* __restrict__ H,
    const float* __restrict__ s_q,
    const float* __restrict__ precip,
    float* __restrict__ H_new,
    float* __restrict__ net_out)
{
    const int i = blockIdx.x * 256 + threadIdx.x;  // bucket
    const float4* q4 = reinterpret_cast<const float4*>(s_q);

    const float4 a = q4[i * 2];
    const float4 b = q4[i * 2 + 1];
    const float of = ((a.x + a.y) + (a.z + a.w)) + ((b.x + b.y) + (b.z + b.w));

    float infl;
    if (i == 0) {
        infl = precip[0];
    } else {
        const float4 c = q4[i * 2 - 2];
        const float4 d = q4[i * 2 - 1];
        infl = ((c.x + c.y) + (c.z + c.w)) + ((d.x + d.y) + (d.z + d.w));
    }
    H_new[i] = H[i] + infl - of;

    float part = (i >= NB - BPL) ? of : 0.0f;
    part += __shfl_xor(part, 1);
    part += __shfl_xor(part, 2);
    part += __shfl_xor(part, 4);
    part += __shfl_xor(part, 8);
    part += __shfl_xor(part, 16);
    part += __shfl_xor(part, 32);

    __shared__ float smem[4];
    const int lane = threadIdx.x & 63;
    const int w    = threadIdx.x >> 6;
    if (lane == 0) smem[w] = part;
    __syncthreads();
    if (threadIdx.x == 0 && blockIdx.x >= ((NB - BPL) >> 8)) {
        atomicAdd(net_out, (smem[0] + smem[1]) + (smem[2] + smem[3]));
    }
}

extern "C" void kernel_launch(void* const* d_in, const int* in_sizes, int n_in,
                              void* d_out, int out_size, void* d_ws, size_t ws_size,
                              hipStream_t stream) {
    const float* H      = (const float*)d_in[0];   // [NB]
    const float* S      = (const float*)d_in[1];   // [NB, NS, 2]
    const float* theta  = (const float*)d_in[2];   // [NB*NS]
    const float* precip = (const float*)d_in[3];   // scalar

    float* out     = (float*)d_out;
    float* H_new   = out;                               // [NB]
    float* s_q     = out + NB;                          // [NB, NS]
    float* net_out = out + NB + (size_t)NB * NS;        // scalar

    // scalar slot is poisoned 0xAA each run -> zero it (capture-safe memset)
    hipMemsetAsync(net_out, 0, sizeof(float), stream);

    const bool have_ws = (ws_size >= (size_t)NB * sizeof(float));
    float* outflows = have_ws ? (float*)d_ws : nullptr;

    spigot_kernel<<<(NB * NS) / 256, 256, 0, stream>>>(H, S, theta, s_q, outflows);

    if (have_ws) {
        head_kernel<<<NB / 1024, 256, 0, stream>>>(H, outflows, precip, H_new, net_out);
    } else {
        head_kernel_nows<<<NB / 256, 256, 0, stream>>>(H, s_q, precip, H_new, net_out);
    }
}